// Round 1
// baseline (707.821 us; speedup 1.0000x reference)
//
#include <hip/hip_runtime.h>
#include <stdint.h>

// GraphBlock_231928234690 — MI355X/gfx950, round 4
// f32 I/O; internal bf16 MFMA.
// NEW this round: k_h writes h_last as a TRANSPOSED bf16 packed tile [k][jp=112]
// directly inside each (h,n) block's own d_out region (first 56 rows of the
// 105-row x 512B column slice; proven self-aliasing: k_attn block (h,n) reads
// exactly the region it later overwrites). k_attn drops the 32KB hT LDS buffer
// and its 32-way-conflict staging: LDS 63KB -> 30.6KB => 5 blocks/CU.
// ws layout unchanged (high water 116,581,376 B):
//   x     @ 0          : 26880*1024 bf16
//   nmask @ 55050240   : 26880 f32
//   Wb    @ 55682048   : 24*1024*128 bf16
//   Wt    @ 61973504   : 8*128*1024 bf16
//   qW1t  @ 64070656   : 24*256*1024 bf16
//   qW2t  @ 76653568   : 24*256*256 bf16
//   r_bf  @ 79799296   : 24*256*256 bf16
//   ga    @ 82945024   : 48*256*128 bf16
//   w12   @ 86090752   : 256*48*1024 bf16 (+slack for k_f B overread)
//   F     @ 111420416  : 256*48*105 f32

typedef unsigned short u16;
typedef __bf16 bf16;
typedef __bf16 bf16x8 __attribute__((ext_vector_type(8)));
typedef float f32x4 __attribute__((ext_vector_type(4)));

#define N_ 256
#define E_ 105
#define D_ 1024
#define H_ 8
#define DH_ 128
#define NE_ 26880

__device__ __forceinline__ u16 f2b(float f) { bf16 h = (bf16)f; return __builtin_bit_cast(u16, h); }
__device__ __forceinline__ float b2f(u16 u) { bf16 h = __builtin_bit_cast(bf16, u); return (float)h; }

#define AS1 __attribute__((address_space(1)))
#define AS3 __attribute__((address_space(3)))

__device__ __forceinline__ void load16_lds(const void* g, void* l) {
  __builtin_amdgcn_global_load_lds((AS1 void*)(unsigned long long)(uintptr_t)g,
                                   (AS3 void*)l, 16, 0, 0);
}

// ---------------------------------------------------------------------------
// 128x128 bf16 GEMM tile: C[128r x 128c] = A(128 x K) * B(128 x K)^T
// lds: caller-provided 16384-u16 (32KB) shared buffer (lA=first half, lB=second)
// ---------------------------------------------------------------------------
__device__ __forceinline__ void gemm128(u16* lds, const u16* A, const u16* B, int K,
                                        int lda, int ldb, f32x4 (&acc)[4][4]) {
  u16* lA = lds;
  u16* lB = lds + 8192;
  const int tid  = threadIdx.x;
  const int lane = tid & 63;
  const int wave = tid >> 6;
  const int ln15 = lane & 15;
  const int lq   = lane >> 4;
  const int wRow = (wave >> 1) * 64;
  const int wCol = (wave & 1) * 64;

  const int iters = K >> 6;
  for (int kt = 0; kt < iters; ++kt) {
    const char* Ab = (const char*)A + kt * 128;
    const char* Bb = (const char*)B + kt * 128;
#pragma unroll
    for (int m = 0; m < 4; ++m) {
      int ci  = m * 256 + tid;
      int row = ci >> 3;
      int g   = (ci & 7) ^ (row & 7);
      char* dstA = (char*)lA + m * 4096 + wave * 1024;
      char* dstB = (char*)lB + m * 4096 + wave * 1024;
      load16_lds(Ab + (long)row * ((long)lda * 2) + g * 16, dstA);
      load16_lds(Bb + (long)row * ((long)ldb * 2) + g * 16, dstB);
    }
    __syncthreads();
#pragma unroll
    for (int ks = 0; ks < 2; ++ks) {
      const int cc = ks * 4 + lq;
      bf16x8 af[4], bfv[4];
#pragma unroll
      for (int i = 0; i < 4; ++i) {
        int r = wRow + i * 16 + ln15;
        af[i] = *(const bf16x8*)&lA[r * 64 + ((cc ^ (r & 7)) << 3)];
        int c = wCol + i * 16 + ln15;
        bfv[i] = *(const bf16x8*)&lB[c * 64 + ((cc ^ (c & 7)) << 3)];
      }
#pragma unroll
      for (int i = 0; i < 4; ++i)
#pragma unroll
        for (int j = 0; j < 4; ++j)
          acc[i][j] = __builtin_amdgcn_mfma_f32_16x16x32_bf16(af[i], bfv[j], acc[i][j], 0, 0, 0);
    }
    __syncthreads();
  }
}

__device__ __forceinline__ void zero_acc(f32x4 (&acc)[4][4]) {
  f32x4 z = {0.f, 0.f, 0.f, 0.f};
#pragma unroll
  for (int i = 0; i < 4; ++i)
#pragma unroll
    for (int j = 0; j < 4; ++j) acc[i][j] = z;
}

// ---------------------------------------------------------------------------
__global__ __launch_bounds__(256) void k_cast(const float* src, u16* dst, long n) {
  long i = ((long)blockIdx.x * 256 + threadIdx.x) * 4;
  if (i >= n) return;
  float4 v = *(const float4*)(src + i);
  ushort4 o;
  o.x = f2b(v.x); o.y = f2b(v.y); o.z = f2b(v.z); o.w = f2b(v.w);
  *(ushort4*)(dst + i) = o;
}

// ---------------------------------------------------------------------------
__global__ __launch_bounds__(256) void k_build(const float* q, const float* para,
                                               const float* sent, const float* ent,
                                               const float* pm, const float* sm,
                                               const float* em, u16* x, float* nmask) {
  long idx = (long)blockIdx.x * 256 + threadIdx.x;
  if (idx >= (long)NE_ * 128) return;
  int ne = (int)(idx >> 7), dc = (int)(idx & 127);
  int n = ne / E_, e = ne - n * E_;
  const float* src;
  if (e == 0)      src = q + (long)n * D_;
  else if (e < 5)  src = para + (long)(n * 4 + (e - 1)) * D_;
  else if (e < 45) src = sent + (long)(n * 40 + (e - 5)) * D_;
  else             src = ent + (long)(n * 60 + (e - 45)) * D_;
  float4 v0 = *(const float4*)(src + dc * 8);
  float4 v1 = *(const float4*)(src + dc * 8 + 4);
  uint4 o;
  o.x = (unsigned)f2b(v0.x) | ((unsigned)f2b(v0.y) << 16);
  o.y = (unsigned)f2b(v0.z) | ((unsigned)f2b(v0.w) << 16);
  o.z = (unsigned)f2b(v1.x) | ((unsigned)f2b(v1.y) << 16);
  o.w = (unsigned)f2b(v1.z) | ((unsigned)f2b(v1.w) << 16);
  *(uint4*)(x + (long)ne * D_ + dc * 8) = o;
  if (dc == 0) {
    float mv;
    if (e == 0)      mv = 1.f;
    else if (e < 5)  mv = pm[n * 4 + e - 1];
    else if (e < 45) mv = sm[n * 40 + e - 5];
    else             mv = em[n * 60 + e - 45];
    nmask[ne] = mv;
  }
}

// ---------------------------------------------------------------------------
__global__ __launch_bounds__(256) void k_tr(const float* src, u16* dst, int R, int C,
                                            long sStr, long dStr) {
  __shared__ u16 t[32][33];
  const int bz = blockIdx.y;
  const int tilesC = C >> 5;
  const int tr = (blockIdx.x / tilesC) << 5;
  const int tc = (blockIdx.x % tilesC) << 5;
  const int lr = threadIdx.x >> 5;
  const int lc = threadIdx.x & 31;
#pragma unroll
  for (int i = 0; i < 4; ++i)
    t[lr + i * 8][lc] = f2b(src[bz * sStr + (long)(tr + lr + i * 8) * C + tc + lc]);
  __syncthreads();
#pragma unroll
  for (int i = 0; i < 4; ++i)
    dst[bz * dStr + (long)(tc + lr + i * 8) * R + tr + lc] = t[lc][lr + i * 8];
}

// ---------------------------------------------------------------------------
// k_qw1: r[ht][n][m] = relu( x(e=0 rows, lda=105*1024) @ qW1t[ht]^T )  96 blocks
// ---------------------------------------------------------------------------
__global__ __launch_bounds__(256) void k_qw1(const u16* x, const u16* qW1t, u16* r_bf) {
  __shared__ u16 shm[16384];
  const int bx = blockIdx.x;
  const int ht = bx >> 2, nt = (bx >> 1) & 1, mt = bx & 1;
  f32x4 acc[4][4];
  zero_acc(acc);
  gemm128(shm, x + (long)nt * 128 * (E_ * D_), qW1t + ((long)ht * 256 + mt * 128) * D_,
          1024, E_ * D_, 1024, acc);
  const int tid = threadIdx.x, lane = tid & 63, wave = tid >> 6;
  const int ln15 = lane & 15, lq = lane >> 4;
  const int wRow = (wave >> 1) * 64, wCol = (wave & 1) * 64;
#pragma unroll
  for (int rt = 0; rt < 4; ++rt)
#pragma unroll
    for (int ct = 0; ct < 4; ++ct)
#pragma unroll
      for (int rg = 0; rg < 4; ++rg) {
        int n = nt * 128 + wRow + rt * 16 + lq * 4 + rg;
        int m = mt * 128 + wCol + ct * 16 + ln15;
        float v = acc[rt][ct][rg];
        if (v < 0.f) v = 0.f;
        r_bf[((long)ht * 256 + n) * 256 + m] = f2b(v);
      }
}

// ---------------------------------------------------------------------------
__global__ __launch_bounds__(256) void k_qw2(const u16* r_bf, const u16* qW2t, const float* a,
                                             u16* ga) {
  __shared__ u16 shm[16384];
  const int bx = blockIdx.x;
  const int ht = bx >> 2, nt = (bx >> 1) & 1, mt = bx & 1;
  f32x4 acc[4][4];
  zero_acc(acc);
  gemm128(shm, r_bf + ((long)ht * 256 + nt * 128) * 256, qW2t + ((long)ht * 256 + mt * 128) * 256,
          256, 256, 256, acc);
  const int tid = threadIdx.x, lane = tid & 63, wave = tid >> 6;
  const int ln15 = lane & 15, lq = lane >> 4;
  const int wRow = (wave >> 1) * 64, wCol = (wave & 1) * 64;
#pragma unroll
  for (int rt = 0; rt < 4; ++rt)
#pragma unroll
    for (int ct = 0; ct < 4; ++ct)
#pragma unroll
      for (int rg = 0; rg < 4; ++rg) {
        int n = nt * 128 + wRow + rt * 16 + lq * 4 + rg;
        int m = mt * 128 + wCol + ct * 16 + ln15;
        float v = acc[rt][ct][rg];
        float sig = 1.f / (1.f + __expf(-v));
        float gv = sig * a[ht * 256 + m];
        int s = m >> 7, kk = m & 127;
        ga[(((long)ht * 2 + s) * 256 + n) * 128 + kk] = f2b(gv);
      }
}

// ---------------------------------------------------------------------------
__global__ __launch_bounds__(256) void k_w12(const u16* ga, const u16* Wb, u16* w12) {
  __shared__ u16 shm[16384];
  const int bx = blockIdx.x;
  const int c = bx >> 4, r2 = bx & 15;
  const int nt = r2 >> 3, dt = r2 & 7;
  const int ht = c >> 1;
  f32x4 acc[4][4];
  zero_acc(acc);
  gemm128(shm, ga + ((long)c * 256 + nt * 128) * 128, Wb + (long)ht * 131072 + dt * 128 * 128,
          128, 128, 128, acc);
  const int tid = threadIdx.x, lane = tid & 63, wave = tid >> 6;
  const int ln15 = lane & 15, lq = lane >> 4;
  const int wRow = (wave >> 1) * 64, wCol = (wave & 1) * 64;
#pragma unroll
  for (int rt = 0; rt < 4; ++rt)
#pragma unroll
    for (int ct = 0; ct < 4; ++ct)
#pragma unroll
      for (int rg = 0; rg < 4; ++rg) {
        int n = nt * 128 + wRow + rt * 16 + lq * 4 + rg;
        int d = dt * 128 + wCol + ct * 16 + ln15;
        w12[((long)n * 48 + c) * 1024 + d] = f2b(acc[rt][ct][rg]);
      }
}

// ---------------------------------------------------------------------------
__global__ __launch_bounds__(256) void k_f(const u16* x, const u16* w12, float* F) {
  __shared__ u16 shm[16384];
  const int n = blockIdx.x;
  f32x4 acc[4][4];
  zero_acc(acc);
  gemm128(shm, x + (long)n * E_ * D_, w12 + (long)n * 48 * 1024, 1024, 1024, 1024, acc);
  const int tid = threadIdx.x, lane = tid & 63, wave = tid >> 6;
  const int ln15 = lane & 15, lq = lane >> 4;
  const int wRow = (wave >> 1) * 64, wCol = (wave & 1) * 64;
#pragma unroll
  for (int rt = 0; rt < 4; ++rt)
#pragma unroll
    for (int ct = 0; ct < 4; ++ct)
#pragma unroll
      for (int rg = 0; rg < 4; ++rg) {
        int e = wRow + rt * 16 + lq * 4 + rg;
        int c = wCol + ct * 16 + ln15;
        if (e < 105 && c < 48) F[((long)n * 48 + c) * 105 + e] = acc[rt][ct][rg];
      }
}

// ---------------------------------------------------------------------------
// k_h: h_last -> packed transposed bf16 tile inside d_out.
// Tile (h,n): 128k x 112j bf16 (j 105..111 zero), t = k*224 + j*2 (28672 B),
// placed at out bytes ((n*105 + (t>>9))<<12) + (h<<9) + (t&511)  [rows 0..55 of
// the block's column slice — read then overwritten ONLY by k_attn block (h,n)].
// Transpose via reuse of the 32KB gemm LDS with XOR swizzle (bank-conflict-free).
// ---------------------------------------------------------------------------
__global__ __launch_bounds__(256) void k_h(const u16* x, const u16* Wt, const float* nmask,
                                           float* out) {
  __shared__ u16 shm[16384];
  const int bx = blockIdx.x;
  const int h = bx / 210;
  const int ne0 = (bx % 210) * 128;
  f32x4 acc[4][4];
  zero_acc(acc);
  gemm128(shm, x + (long)ne0 * D_, Wt + (long)h * DH_ * D_, 1024, 1024, 1024, acc);
  const int tid = threadIdx.x, lane = tid & 63, wave = tid >> 6;
  const int ln15 = lane & 15, lq = lane >> 4;
  const int wRow = (wave >> 1) * 64, wCol = (wave & 1) * 64;
  // stage transposed bf16 tile: shm[k*128 + (ne ^ ((k&15)<<3))]
#pragma unroll
  for (int rt = 0; rt < 4; ++rt)
#pragma unroll
    for (int ct = 0; ct < 4; ++ct)
#pragma unroll
      for (int rg = 0; rg < 4; ++rg) {
        int nel = wRow + rt * 16 + lq * 4 + rg;
        int k   = wCol + ct * 16 + ln15;
        shm[k * 128 + (nel ^ ((k & 15) << 3))] = f2b(acc[rt][ct][rg]);
      }
  __syncthreads();
  char* ob = (char*)out;
  for (int it = tid; it < 16384; it += 256) {
    int k = it >> 7, nel = it & 127;
    int ne = ne0 + nel;
    int n = ne / 105;
    int j = ne - n * 105;
    int t = k * 224 + j * 2;
    long gb = ((long)(n * 105 + (t >> 9)) << 12) + ((long)h << 9) + (t & 511);
    u16 v = shm[k * 128 + (nel ^ ((k & 15) << 3))];
    float mv = nmask[ne];
    *(u16*)(ob + gb) = (mv != 0.f) ? v : (u16)0;
    if (j == 104) {
      // zero-fill j = 105..111 padding for this (h,n,k) so B reads stay finite
#pragma unroll
      for (int p = 1; p <= 7; ++p) {
        int tp = t + p * 2;
        long gp = ((long)(n * 105 + (tp >> 9)) << 12) + ((long)h << 9) + (tp & 511);
        *(u16*)(ob + gp) = 0;
      }
    }
  }
}

// ---------------------------------------------------------------------------
// k_attn: per (h,n): wave-parallel softmax (adj prefetch, shfl butterflies)
// -> coefs bf16 in LDS -> MFMA PV reading the packed bf16 h_last tile straight
// from d_out (L1-resident 28KB) -> relu -> +x residual. 2048 blocks.
// LDS 30.6KB => 5 blocks/CU (was 63KB => 2). Mapping h=bx>>8,n=bx&255 keeps
// all 8 h of one n on the same XCD (256 % 8 == 0) for adj L2 reuse.
// ---------------------------------------------------------------------------
__global__ __launch_bounds__(256) void k_attn(const float* F, const int* adj, const u16* x,
                                              float* out) {
  const int h = blockIdx.x >> 8;
  const int n = blockIdx.x & 255;
  __shared__ u16 cb[112 * 128];
  __shared__ float f1s[3][112];
  __shared__ float f2s[3][112];
  const int tid = threadIdx.x;
  const int lane = tid & 63, wave = tid >> 6;

  // ---- phase A: stage F rows, zero cb ----
  for (int i = tid; i < 630; i += 256) {
    int t = i / 210;
    int rm = i - t * 210;
    int s = rm / 105;
    int e = rm - s * 105;
    float v = F[((long)n * 48 + (h * 3 + t) * 2 + s) * 105 + e];
    if (s == 0) f1s[t][e] = v; else f2s[t][e] = v;
  }
  {
    unsigned* cbz = (unsigned*)cb;
    for (int i = tid; i < 112 * 64; i += 256) cbz[i] = 0;
  }
  __syncthreads();

  // ---- phase B: wave w owns rows i=w,w+4,..; lane owns cols j=lane, 64+lane ----
  {
    const int* abase = adj + (long)n * (E_ * E_);
    const int j1 = 64 + lane;
    const bool j1v = lane < 41;
    float f20a = f2s[0][lane], f20b = f2s[1][lane], f20c = f2s[2][lane];
    float f21a = 0.f, f21b = 0.f, f21c = 0.f;
    if (j1v) { f21a = f2s[0][j1]; f21b = f2s[1][j1]; f21c = f2s[2][j1]; }
    int i = wave;
    int av0 = abase[i * E_ + lane];
    int av1 = j1v ? abase[i * E_ + j1] : 0;
    while (i < 105) {
      const int inext = i + 4;
      int bv0 = 0, bv1 = 0;
      if (inext < 105) {
        bv0 = abase[inext * E_ + lane];
        bv1 = j1v ? abase[inext * E_ + j1] : 0;
      }
      float f11 = f1s[0][i], f12 = f1s[1][i], f13 = f1s[2][i];
      float s0, s1;
      {
        float f1v = (av0 == 1) ? f11 : ((av0 == 2) ? f12 : f13);
        float f2v = (av0 == 1) ? f20a : ((av0 == 2) ? f20b : f20c);
        float s = f1v + f2v;
        s = (s < 0.f) ? 0.2f * s : s;
        s0 = (av0 > 0) ? s : -1e30f;
      }
      {
        float f1v = (av1 == 1) ? f11 : ((av1 == 2) ? f12 : f13);
        float f2v = (av1 == 1) ? f21a : ((av1 == 2) ? f21b : f21c);
        float s = f1v + f2v;
        s = (s < 0.f) ? 0.2f * s : s;
        s1 = (av1 > 0) ? s : -1e30f;
      }
      float m = fmaxf(s0, s1);
#pragma unroll
      for (int d = 1; d < 64; d <<= 1) m = fmaxf(m, __shfl_xor(m, d));
      float e0 = __expf(s0 - m);
      float e1 = j1v ? __expf(s1 - m) : 0.f;
      float sum = e0 + e1;
#pragma unroll
      for (int d = 1; d < 64; d <<= 1) sum += __shfl_xor(sum, d);
      float inv = 1.f / sum;
      const int rsw = i & 15;
      cb[i * 128 + ((((lane >> 3) ^ rsw) << 3) + (lane & 7))] = f2b(e0 * inv);
      if (j1v)
        cb[i * 128 + ((((j1 >> 3) ^ rsw) << 3) + (lane & 7))] = f2b(e1 * inv);
      av0 = bv0; av1 = bv1;
      i = inext;
    }
  }
  __syncthreads();

  // ---- phase C: out[i][k] = sum_j coefs[i][j]*hl[j][k] via MFMA ----
  // B fragments read straight from the packed bf16 tile in d_out.
  const char* hb = (const char*)out + (((long)n * 105) << 12) + ((long)h << 9);
  const int ln15 = lane & 15, lq = lane >> 4;
  const int nmt = (wave < 3) ? 2 : 1;
  f32x4 acc[2][8];
  {
    f32x4 z = {0.f, 0.f, 0.f, 0.f};
#pragma unroll
    for (int a_ = 0; a_ < 2; ++a_)
#pragma unroll
      for (int b_ = 0; b_ < 8; ++b_) acc[a_][b_] = z;
  }
#pragma unroll
  for (int ks = 0; ks < 4; ++ks) {
    const int cc = ks * 4 + lq;
    // clamp invalid chunks (cc 14,15): B reads chunk 0 (finite); matching A
    // chunks are never-written cb positions (swizzle is bijective) => zero.
    const int ccb = (cc < 14) ? cc : 0;
    bf16x8 bfr[8];
#pragma unroll
    for (int jn = 0; jn < 8; ++jn) {
      int k = jn * 16 + ln15;
      int t = k * 224 + ccb * 16;
      bfr[jn] = *(const bf16x8*)(hb + ((long)(t >> 9) << 12) + (t & 511));
    }
#pragma unroll
    for (int im = 0; im < 2; ++im) {
      if (im < nmt) {
        int i = (wave + im * 4) * 16 + ln15;
        bf16x8 af = *(const bf16x8*)&cb[i * 128 + ((cc ^ (i & 15)) << 3)];
#pragma unroll
        for (int jn = 0; jn < 8; ++jn)
          acc[im][jn] = __builtin_amdgcn_mfma_f32_16x16x32_bf16(af, bfr[jn], acc[im][jn], 0, 0, 0);
      }
    }
  }
  // all waves must finish reading the packed tile before anyone overwrites out
  __syncthreads();
  for (int im = 0; im < nmt; ++im)
    for (int jn = 0; jn < 8; ++jn)
#pragma unroll
      for (int rg = 0; rg < 4; ++rg) {
        int i = (wave + im * 4) * 16 + lq * 4 + rg;
        if (i < 105) {
          int k = jn * 16 + ln15;
          long off = ((long)(n * E_ + i)) * D_ + h * DH_ + k;
          float v = acc[im][jn][rg];
          v = v < 0.f ? 0.f : v;
          out[off] = v + b2f(x[off]);
        }
      }
}

// ---------------------------------------------------------------------------
extern "C" void kernel_launch(void* const* d_in, const int* in_sizes, int n_in,
                              void* d_out, int out_size, void* d_ws, size_t ws_size,
                              hipStream_t stream) {
  const float* q    = (const float*)d_in[0];
  const float* para = (const float*)d_in[1];
  const float* sent = (const float*)d_in[2];
  const float* ent  = (const float*)d_in[3];
  const float* pm   = (const float*)d_in[4];
  const float* sm   = (const float*)d_in[5];
  const float* em   = (const float*)d_in[6];
  const int*   adj  = (const int*)d_in[7];
  const float* W    = (const float*)d_in[8];
  const float* a    = (const float*)d_in[9];
  const float* qW1  = (const float*)d_in[10];
  const float* qW2  = (const float*)d_in[11];
  float* out = (float*)d_out;
  char* ws = (char*)d_ws;

  u16*   x     = (u16*)(ws);
  float* nmask = (float*)(ws + 55050240);
  u16*   Wb    = (u16*)(ws + 55682048);
  u16*   Wt    = (u16*)(ws + 61973504);
  u16*   qW1t  = (u16*)(ws + 64070656);
  u16*   qW2t  = (u16*)(ws + 76653568);
  u16*   r_bf  = (u16*)(ws + 79799296);
  u16*   ga    = (u16*)(ws + 82945024);
  u16*   w12   = (u16*)(ws + 86090752);
  float* F     = (float*)(ws + 111420416);

  k_build<<<13440, 256, 0, stream>>>(q, para, sent, ent, pm, sm, em, x, nmask);
  k_cast<<<3072, 256, 0, stream>>>(W, Wb, 3145728);
  k_tr<<<dim3(256, 24), 256, 0, stream>>>(qW1, qW1t, 1024, 256, 262144, 262144);
  k_tr<<<dim3(64, 24), 256, 0, stream>>>(qW2, qW2t, 256, 256, 65536, 65536);
  k_tr<<<dim3(128, 8), 256, 0, stream>>>(W + 262144, Wt, 1024, 128, 393216, 131072);
  k_qw1<<<96, 256, 0, stream>>>(x, qW1t, r_bf);
  k_qw2<<<96, 256, 0, stream>>>(r_bf, qW2t, a, ga);
  k_w12<<<768, 256, 0, stream>>>(ga, Wb, w12);
  k_f<<<256, 256, 0, stream>>>(x, w12, F);
  k_h<<<1680, 256, 0, stream>>>(x, Wt, nmask, out);
  k_attn<<<2048, 256, 0, stream>>>(F, adj, x, out);
}

// Round 3
// 661.033 us; speedup vs baseline: 1.0708x; 1.0708x over previous
//
#include <hip/hip_runtime.h>
#include <stdint.h>

// GraphBlock_231928234690 — MI355X/gfx950, round 6 (= round-5 source, resubmitted
// after infra-failure; no counter evidence against it, audit found no fault).
// f32 I/O; internal bf16 MFMA.
// k_attn: coalesced full-line out writes via LDS f32 restage (kills 4.25x
// partial-line write amplification) + 16-lane-group softmax (7 iters, was 27).
// ws layout unchanged (high water 116,581,376 B).

typedef unsigned short u16;
typedef __bf16 bf16;
typedef __bf16 bf16x8 __attribute__((ext_vector_type(8)));
typedef float f32x4 __attribute__((ext_vector_type(4)));

#define N_ 256
#define E_ 105
#define D_ 1024
#define H_ 8
#define DH_ 128
#define NE_ 26880

__device__ __forceinline__ u16 f2b(float f) { bf16 h = (bf16)f; return __builtin_bit_cast(u16, h); }
__device__ __forceinline__ float b2f(u16 u) { bf16 h = __builtin_bit_cast(bf16, u); return (float)h; }

#define AS1 __attribute__((address_space(1)))
#define AS3 __attribute__((address_space(3)))

__device__ __forceinline__ void load16_lds(const void* g, void* l) {
  __builtin_amdgcn_global_load_lds((AS1 void*)(unsigned long long)(uintptr_t)g,
                                   (AS3 void*)l, 16, 0, 0);
}

// ---------------------------------------------------------------------------
// 128x128 bf16 GEMM tile: C[128r x 128c] = A(128 x K) * B(128 x K)^T
// lds: caller-provided 16384-u16 (32KB) shared buffer (lA=first half, lB=second)
// ---------------------------------------------------------------------------
__device__ __forceinline__ void gemm128(u16* lds, const u16* A, const u16* B, int K,
                                        int lda, int ldb, f32x4 (&acc)[4][4]) {
  u16* lA = lds;
  u16* lB = lds + 8192;
  const int tid  = threadIdx.x;
  const int lane = tid & 63;
  const int wave = tid >> 6;
  const int ln15 = lane & 15;
  const int lq   = lane >> 4;
  const int wRow = (wave >> 1) * 64;
  const int wCol = (wave & 1) * 64;

  const int iters = K >> 6;
  for (int kt = 0; kt < iters; ++kt) {
    const char* Ab = (const char*)A + kt * 128;
    const char* Bb = (const char*)B + kt * 128;
#pragma unroll
    for (int m = 0; m < 4; ++m) {
      int ci  = m * 256 + tid;
      int row = ci >> 3;
      int g   = (ci & 7) ^ (row & 7);
      char* dstA = (char*)lA + m * 4096 + wave * 1024;
      char* dstB = (char*)lB + m * 4096 + wave * 1024;
      load16_lds(Ab + (long)row * ((long)lda * 2) + g * 16, dstA);
      load16_lds(Bb + (long)row * ((long)ldb * 2) + g * 16, dstB);
    }
    __syncthreads();
#pragma unroll
    for (int ks = 0; ks < 2; ++ks) {
      const int cc = ks * 4 + lq;
      bf16x8 af[4], bfv[4];
#pragma unroll
      for (int i = 0; i < 4; ++i) {
        int r = wRow + i * 16 + ln15;
        af[i] = *(const bf16x8*)&lA[r * 64 + ((cc ^ (r & 7)) << 3)];
        int c = wCol + i * 16 + ln15;
        bfv[i] = *(const bf16x8*)&lB[c * 64 + ((cc ^ (c & 7)) << 3)];
      }
#pragma unroll
      for (int i = 0; i < 4; ++i)
#pragma unroll
        for (int j = 0; j < 4; ++j)
          acc[i][j] = __builtin_amdgcn_mfma_f32_16x16x32_bf16(af[i], bfv[j], acc[i][j], 0, 0, 0);
    }
    __syncthreads();
  }
}

__device__ __forceinline__ void zero_acc(f32x4 (&acc)[4][4]) {
  f32x4 z = {0.f, 0.f, 0.f, 0.f};
#pragma unroll
  for (int i = 0; i < 4; ++i)
#pragma unroll
    for (int j = 0; j < 4; ++j) acc[i][j] = z;
}

// ---------------------------------------------------------------------------
__global__ __launch_bounds__(256) void k_cast(const float* src, u16* dst, long n) {
  long i = ((long)blockIdx.x * 256 + threadIdx.x) * 4;
  if (i >= n) return;
  float4 v = *(const float4*)(src + i);
  ushort4 o;
  o.x = f2b(v.x); o.y = f2b(v.y); o.z = f2b(v.z); o.w = f2b(v.w);
  *(ushort4*)(dst + i) = o;
}

// ---------------------------------------------------------------------------
__global__ __launch_bounds__(256) void k_build(const float* q, const float* para,
                                               const float* sent, const float* ent,
                                               const float* pm, const float* sm,
                                               const float* em, u16* x, float* nmask) {
  long idx = (long)blockIdx.x * 256 + threadIdx.x;
  if (idx >= (long)NE_ * 128) return;
  int ne = (int)(idx >> 7), dc = (int)(idx & 127);
  int n = ne / E_, e = ne - n * E_;
  const float* src;
  if (e == 0)      src = q + (long)n * D_;
  else if (e < 5)  src = para + (long)(n * 4 + (e - 1)) * D_;
  else if (e < 45) src = sent + (long)(n * 40 + (e - 5)) * D_;
  else             src = ent + (long)(n * 60 + (e - 45)) * D_;
  float4 v0 = *(const float4*)(src + dc * 8);
  float4 v1 = *(const float4*)(src + dc * 8 + 4);
  uint4 o;
  o.x = (unsigned)f2b(v0.x) | ((unsigned)f2b(v0.y) << 16);
  o.y = (unsigned)f2b(v0.z) | ((unsigned)f2b(v0.w) << 16);
  o.z = (unsigned)f2b(v1.x) | ((unsigned)f2b(v1.y) << 16);
  o.w = (unsigned)f2b(v1.z) | ((unsigned)f2b(v1.w) << 16);
  *(uint4*)(x + (long)ne * D_ + dc * 8) = o;
  if (dc == 0) {
    float mv;
    if (e == 0)      mv = 1.f;
    else if (e < 5)  mv = pm[n * 4 + e - 1];
    else if (e < 45) mv = sm[n * 40 + e - 5];
    else             mv = em[n * 60 + e - 45];
    nmask[ne] = mv;
  }
}

// ---------------------------------------------------------------------------
__global__ __launch_bounds__(256) void k_tr(const float* src, u16* dst, int R, int C,
                                            long sStr, long dStr) {
  __shared__ u16 t[32][33];
  const int bz = blockIdx.y;
  const int tilesC = C >> 5;
  const int tr = (blockIdx.x / tilesC) << 5;
  const int tc = (blockIdx.x % tilesC) << 5;
  const int lr = threadIdx.x >> 5;
  const int lc = threadIdx.x & 31;
#pragma unroll
  for (int i = 0; i < 4; ++i)
    t[lr + i * 8][lc] = f2b(src[bz * sStr + (long)(tr + lr + i * 8) * C + tc + lc]);
  __syncthreads();
#pragma unroll
  for (int i = 0; i < 4; ++i)
    dst[bz * dStr + (long)(tc + lr + i * 8) * R + tr + lc] = t[lc][lr + i * 8];
}

// ---------------------------------------------------------------------------
// k_qw1: r[ht][n][m] = relu( x(e=0 rows, lda=105*1024) @ qW1t[ht]^T )  96 blocks
// ---------------------------------------------------------------------------
__global__ __launch_bounds__(256) void k_qw1(const u16* x, const u16* qW1t, u16* r_bf) {
  __shared__ u16 shm[16384];
  const int bx = blockIdx.x;
  const int ht = bx >> 2, nt = (bx >> 1) & 1, mt = bx & 1;
  f32x4 acc[4][4];
  zero_acc(acc);
  gemm128(shm, x + (long)nt * 128 * (E_ * D_), qW1t + ((long)ht * 256 + mt * 128) * D_,
          1024, E_ * D_, 1024, acc);
  const int tid = threadIdx.x, lane = tid & 63, wave = tid >> 6;
  const int ln15 = lane & 15, lq = lane >> 4;
  const int wRow = (wave >> 1) * 64, wCol = (wave & 1) * 64;
#pragma unroll
  for (int rt = 0; rt < 4; ++rt)
#pragma unroll
    for (int ct = 0; ct < 4; ++ct)
#pragma unroll
      for (int rg = 0; rg < 4; ++rg) {
        int n = nt * 128 + wRow + rt * 16 + lq * 4 + rg;
        int m = mt * 128 + wCol + ct * 16 + ln15;
        float v = acc[rt][ct][rg];
        if (v < 0.f) v = 0.f;
        r_bf[((long)ht * 256 + n) * 256 + m] = f2b(v);
      }
}

// ---------------------------------------------------------------------------
__global__ __launch_bounds__(256) void k_qw2(const u16* r_bf, const u16* qW2t, const float* a,
                                             u16* ga) {
  __shared__ u16 shm[16384];
  const int bx = blockIdx.x;
  const int ht = bx >> 2, nt = (bx >> 1) & 1, mt = bx & 1;
  f32x4 acc[4][4];
  zero_acc(acc);
  gemm128(shm, r_bf + ((long)ht * 256 + nt * 128) * 256, qW2t + ((long)ht * 256 + mt * 128) * 256,
          256, 256, 256, acc);
  const int tid = threadIdx.x, lane = tid & 63, wave = tid >> 6;
  const int ln15 = lane & 15, lq = lane >> 4;
  const int wRow = (wave >> 1) * 64, wCol = (wave & 1) * 64;
#pragma unroll
  for (int rt = 0; rt < 4; ++rt)
#pragma unroll
    for (int ct = 0; ct < 4; ++ct)
#pragma unroll
      for (int rg = 0; rg < 4; ++rg) {
        int n = nt * 128 + wRow + rt * 16 + lq * 4 + rg;
        int m = mt * 128 + wCol + ct * 16 + ln15;
        float v = acc[rt][ct][rg];
        float sig = 1.f / (1.f + __expf(-v));
        float gv = sig * a[ht * 256 + m];
        int s = m >> 7, kk = m & 127;
        ga[(((long)ht * 2 + s) * 256 + n) * 128 + kk] = f2b(gv);
      }
}

// ---------------------------------------------------------------------------
__global__ __launch_bounds__(256) void k_w12(const u16* ga, const u16* Wb, u16* w12) {
  __shared__ u16 shm[16384];
  const int bx = blockIdx.x;
  const int c = bx >> 4, r2 = bx & 15;
  const int nt = r2 >> 3, dt = r2 & 7;
  const int ht = c >> 1;
  f32x4 acc[4][4];
  zero_acc(acc);
  gemm128(shm, ga + ((long)c * 256 + nt * 128) * 128, Wb + (long)ht * 131072 + dt * 128 * 128,
          128, 128, 128, acc);
  const int tid = threadIdx.x, lane = tid & 63, wave = tid >> 6;
  const int ln15 = lane & 15, lq = lane >> 4;
  const int wRow = (wave >> 1) * 64, wCol = (wave & 1) * 64;
#pragma unroll
  for (int rt = 0; rt < 4; ++rt)
#pragma unroll
    for (int ct = 0; ct < 4; ++ct)
#pragma unroll
      for (int rg = 0; rg < 4; ++rg) {
        int n = nt * 128 + wRow + rt * 16 + lq * 4 + rg;
        int d = dt * 128 + wCol + ct * 16 + ln15;
        w12[((long)n * 48 + c) * 1024 + d] = f2b(acc[rt][ct][rg]);
      }
}

// ---------------------------------------------------------------------------
__global__ __launch_bounds__(256) void k_f(const u16* x, const u16* w12, float* F) {
  __shared__ u16 shm[16384];
  const int n = blockIdx.x;
  f32x4 acc[4][4];
  zero_acc(acc);
  gemm128(shm, x + (long)n * E_ * D_, w12 + (long)n * 48 * 1024, 1024, 1024, 1024, acc);
  const int tid = threadIdx.x, lane = tid & 63, wave = tid >> 6;
  const int ln15 = lane & 15, lq = lane >> 4;
  const int wRow = (wave >> 1) * 64, wCol = (wave & 1) * 64;
#pragma unroll
  for (int rt = 0; rt < 4; ++rt)
#pragma unroll
    for (int ct = 0; ct < 4; ++ct)
#pragma unroll
      for (int rg = 0; rg < 4; ++rg) {
        int e = wRow + rt * 16 + lq * 4 + rg;
        int c = wCol + ct * 16 + ln15;
        if (e < 105 && c < 48) F[((long)n * 48 + c) * 105 + e] = acc[rt][ct][rg];
      }
}

// ---------------------------------------------------------------------------
// k_h: h_last -> packed transposed bf16 tile inside d_out.
// Tile (h,n): 128k x 112j bf16 (j 105..111 zero), t = k*224 + j*2 (28672 B),
// placed at out bytes ((n*105 + (t>>9))<<12) + (h<<9) + (t&511)  [rows 0..55 of
// the block's column slice — read then overwritten ONLY by k_attn block (h,n)].
// ---------------------------------------------------------------------------
__global__ __launch_bounds__(256) void k_h(const u16* x, const u16* Wt, const float* nmask,
                                           float* out) {
  __shared__ u16 shm[16384];
  const int bx = blockIdx.x;
  const int h = bx / 210;
  const int ne0 = (bx % 210) * 128;
  f32x4 acc[4][4];
  zero_acc(acc);
  gemm128(shm, x + (long)ne0 * D_, Wt + (long)h * DH_ * D_, 1024, 1024, 1024, acc);
  const int tid = threadIdx.x, lane = tid & 63, wave = tid >> 6;
  const int ln15 = lane & 15, lq = lane >> 4;
  const int wRow = (wave >> 1) * 64, wCol = (wave & 1) * 64;
  // stage transposed bf16 tile: shm[k*128 + (ne ^ ((k&15)<<3))]
#pragma unroll
  for (int rt = 0; rt < 4; ++rt)
#pragma unroll
    for (int ct = 0; ct < 4; ++ct)
#pragma unroll
      for (int rg = 0; rg < 4; ++rg) {
        int nel = wRow + rt * 16 + lq * 4 + rg;
        int k   = wCol + ct * 16 + ln15;
        shm[k * 128 + (nel ^ ((k & 15) << 3))] = f2b(acc[rt][ct][rg]);
      }
  __syncthreads();
  char* ob = (char*)out;
  for (int it = tid; it < 16384; it += 256) {
    int k = it >> 7, nel = it & 127;
    int ne = ne0 + nel;
    int n = ne / 105;
    int j = ne - n * 105;
    int t = k * 224 + j * 2;
    long gb = ((long)(n * 105 + (t >> 9)) << 12) + ((long)h << 9) + (t & 511);
    u16 v = shm[k * 128 + (nel ^ ((k & 15) << 3))];
    float mv = nmask[ne];
    *(u16*)(ob + gb) = (mv != 0.f) ? v : (u16)0;
    if (j == 104) {
#pragma unroll
      for (int p = 1; p <= 7; ++p) {
        int tp = t + p * 2;
        long gp = ((long)(n * 105 + (tp >> 9)) << 12) + ((long)h << 9) + (tp & 511);
        *(u16*)(ob + gp) = 0;
      }
    }
  }
}

// ---------------------------------------------------------------------------
// k_attn: per (h,n). Phase B: 16-lane-group softmax (4 rows/wave/iter, 7 iters).
// Phase C: MFMA PV (B from packed bf16 tile in d_out) -> relu -> LDS f32 stage
// (reuse cb, stride 132) -> coalesced float4 writes (+bf16 residual).
// LDS 31744 B. 2048 blocks.
// ---------------------------------------------------------------------------
__global__ __launch_bounds__(256) void k_attn(const float* F, const int* adj, const u16* x,
                                              float* out) {
  const int h = blockIdx.x >> 8;
  const int n = blockIdx.x & 255;
  __shared__ u16 cb[112 * 128];
  __shared__ float f1s[3][112];
  __shared__ float f2s[3][112];
  const int tid = threadIdx.x;
  const int lane = tid & 63, wave = tid >> 6;

  // ---- phase A: stage F rows, zero cb ----
  for (int i = tid; i < 630; i += 256) {
    int t = i / 210;
    int rm = i - t * 210;
    int s = rm / 105;
    int e = rm - s * 105;
    float v = F[((long)n * 48 + (h * 3 + t) * 2 + s) * 105 + e];
    if (s == 0) f1s[t][e] = v; else f2s[t][e] = v;
  }
  {
    unsigned* cbz = (unsigned*)cb;
    for (int i = tid; i < 112 * 64; i += 256) cbz[i] = 0;
  }
  __syncthreads();

  // ---- phase B: 16-lane groups; row i = it*16 + wave*4 + g; lane owns 7 cols ----
  {
    const int* abase = adj + (long)n * (E_ * E_);
    const int g  = lane >> 4;
    const int lg = lane & 15;
    float f2r[3][7];
#pragma unroll
    for (int m = 0; m < 7; ++m) {
      int j = lg + m * 16;
      bool jv = j < 105;
#pragma unroll
      for (int t = 0; t < 3; ++t) f2r[t][m] = jv ? f2s[t][j] : 0.f;
    }
    for (int it = 0; it < 7; ++it) {
      int i = it * 16 + wave * 4 + g;
      bool iv = i < 105;
      int ir = iv ? i : 0;
      int av[7];
#pragma unroll
      for (int m = 0; m < 7; ++m) {
        int j = lg + m * 16;
        av[m] = (iv && j < 105) ? abase[ir * E_ + j] : 0;
      }
      float f11 = f1s[0][ir], f12 = f1s[1][ir], f13 = f1s[2][ir];
      float s[7];
#pragma unroll
      for (int m = 0; m < 7; ++m) {
        int a_ = av[m];
        float f1v = (a_ == 1) ? f11 : ((a_ == 2) ? f12 : f13);
        float f2v = (a_ == 1) ? f2r[0][m] : ((a_ == 2) ? f2r[1][m] : f2r[2][m]);
        float sv = f1v + f2v;
        sv = (sv < 0.f) ? 0.2f * sv : sv;
        s[m] = (a_ > 0) ? sv : -1e30f;
      }
      float mm = s[0];
#pragma unroll
      for (int m = 1; m < 7; ++m) mm = fmaxf(mm, s[m]);
#pragma unroll
      for (int d = 1; d < 16; d <<= 1) mm = fmaxf(mm, __shfl_xor(mm, d));
      float e[7];
      float sum = 0.f;
#pragma unroll
      for (int m = 0; m < 7; ++m) {
        int j = lg + m * 16;
        e[m] = (j < 105) ? __expf(s[m] - mm) : 0.f;
        sum += e[m];
      }
#pragma unroll
      for (int d = 1; d < 16; d <<= 1) sum += __shfl_xor(sum, d);
      float inv = 1.f / sum;
      if (iv) {
        const int rsw = i & 15;
#pragma unroll
        for (int m = 0; m < 7; ++m) {
          int j = lg + m * 16;
          if (j < 105)
            cb[i * 128 + ((((j >> 3) ^ rsw) << 3) + (j & 7))] = f2b(e[m] * inv);
        }
      }
    }
  }
  __syncthreads();

  // ---- phase C: PV via MFMA; B fragments read from packed bf16 tile in d_out ----
  const char* hb = (const char*)out + (((long)n * 105) << 12) + ((long)h << 9);
  const int ln15 = lane & 15, lq = lane >> 4;
  const int nmt = (wave < 3) ? 2 : 1;
  f32x4 acc[2][8];
  {
    f32x4 z = {0.f, 0.f, 0.f, 0.f};
#pragma unroll
    for (int a_ = 0; a_ < 2; ++a_)
#pragma unroll
      for (int b_ = 0; b_ < 8; ++b_) acc[a_][b_] = z;
  }
#pragma unroll
  for (int ks = 0; ks < 4; ++ks) {
    const int cc = ks * 4 + lq;
    const int ccb = (cc < 14) ? cc : 0;  // clamp: matching A chunks are zero
    bf16x8 bfr[8];
#pragma unroll
    for (int jn = 0; jn < 8; ++jn) {
      int k = jn * 16 + ln15;
      int t = k * 224 + ccb * 16;
      bfr[jn] = *(const bf16x8*)(hb + ((long)(t >> 9) << 12) + (t & 511));
    }
#pragma unroll
    for (int im = 0; im < 2; ++im) {
      if (im < nmt) {
        int i = (wave + im * 4) * 16 + ln15;
        bf16x8 af = *(const bf16x8*)&cb[i * 128 + ((cc ^ (i & 15)) << 3)];
#pragma unroll
        for (int jn = 0; jn < 8; ++jn)
          acc[im][jn] = __builtin_amdgcn_mfma_f32_16x16x32_bf16(af, bfr[jn], acc[im][jn], 0, 0, 0);
      }
    }
  }
  // all MFMA reads (cb + packed tile) must complete before cb reuse / out writes
  __syncthreads();

  // ---- phase D: relu(acc) -> LDS f32 (stride 132) -> coalesced float4 writes ----
  float* sf = (float*)cb;
#pragma unroll
  for (int pass = 0; pass < 2; ++pass) {
    const int rbase = pass * 54;
    const int rcnt  = pass ? 51 : 54;
    for (int im = 0; im < nmt; ++im)
#pragma unroll
      for (int jn = 0; jn < 8; ++jn)
#pragma unroll
        for (int rg = 0; rg < 4; ++rg) {
          int i = (wave + im * 4) * 16 + lq * 4 + rg;
          if (i >= rbase && i < rbase + rcnt && i < 105) {
            int k = jn * 16 + ln15;
            float v = acc[im][jn][rg];
            sf[(i - rbase) * 132 + k] = v < 0.f ? 0.f : v;
          }
        }
    __syncthreads();
    for (int c = tid; c < rcnt * 32; c += 256) {
      int r = c >> 5, k4 = (c & 31) << 2;
      int i = rbase + r;
      float4 v = *(const float4*)&sf[r * 132 + k4];
      long xb = ((long)(n * E_ + i)) * D_ + h * DH_ + k4;
      ushort4 xv = *(const ushort4*)&x[xb];
      v.x += b2f(xv.x); v.y += b2f(xv.y); v.z += b2f(xv.z); v.w += b2f(xv.w);
      *(float4*)&out[xb] = v;
    }
    if (pass == 0) __syncthreads();
  }
}

// ---------------------------------------------------------------------------
extern "C" void kernel_launch(void* const* d_in, const int* in_sizes, int n_in,
                              void* d_out, int out_size, void* d_ws, size_t ws_size,
                              hipStream_t stream) {
  const float* q    = (const float*)d_in[0];
  const float* para = (const float*)d_in[1];
  const float* sent = (const float*)d_in[2];
  const float* ent  = (const float*)d_in[3];
  const float* pm   = (const float*)d_in[4];
  const float* sm   = (const float*)d_in[5];
  const float* em   = (const float*)d_in[6];
  const int*   adj  = (const int*)d_in[7];
  const float* W    = (const float*)d_in[8];
  const float* a    = (const float*)d_in[9];
  const float* qW1  = (const float*)d_in[10];
  const float* qW2  = (const float*)d_in[11];
  float* out = (float*)d_out;
  char* ws = (char*)d_ws;

  u16*   x     = (u16*)(ws);
  float* nmask = (float*)(ws + 55050240);
  u16*   Wb    = (u16*)(ws + 55682048);
  u16*   Wt    = (u16*)(ws + 61973504);
  u16*   qW1t  = (u16*)(ws + 64070656);
  u16*   qW2t  = (u16*)(ws + 76653568);
  u16*   r_bf  = (u16*)(ws + 79799296);
  u16*   ga    = (u16*)(ws + 82945024);
  u16*   w12   = (u16*)(ws + 86090752);
  float* F     = (float*)(ws + 111420416);

  k_build<<<13440, 256, 0, stream>>>(q, para, sent, ent, pm, sm, em, x, nmask);
  k_cast<<<3072, 256, 0, stream>>>(W, Wb, 3145728);
  k_tr<<<dim3(256, 24), 256, 0, stream>>>(qW1, qW1t, 1024, 256, 262144, 262144);
  k_tr<<<dim3(64, 24), 256, 0, stream>>>(qW2, qW2t, 256, 256, 65536, 65536);
  k_tr<<<dim3(128, 8), 256, 0, stream>>>(W + 262144, Wt, 1024, 128, 393216, 131072);
  k_qw1<<<96, 256, 0, stream>>>(x, qW1t, r_bf);
  k_qw2<<<96, 256, 0, stream>>>(r_bf, qW2t, a, ga);
  k_w12<<<768, 256, 0, stream>>>(ga, Wb, w12);
  k_f<<<256, 256, 0, stream>>>(x, w12, F);
  k_h<<<1680, 256, 0, stream>>>(x, Wt, nmask, out);
  k_attn<<<2048, 256, 0, stream>>>(F, adj, x, out);
}